// Round 1
// baseline (972.820 us; speedup 1.0000x reference)
//
#include <hip/hip_runtime.h>
#include <math.h>

#define D 128
#define K 128

// One thread per row. x[128] in VGPRs; W read via wave-uniform addresses
// (scalarizable to s_load); distances in fp32 mimicking numpy/BLAS rounding
// order exactly (sequential-FMA dot, pairwise-8 sums, left-to-right d2).
__global__ __launch_bounds__(256, 2) void vq_main_kernel(
    const float* __restrict__ z,
    const float* __restrict__ W,
    float* __restrict__ out,
    int n_rows)
{
    __shared__ float ww_lds[K];
    __shared__ int   best_lds[256];

    const int tid = threadIdx.x;
    const long long row = (long long)blockIdx.x * 256 + tid;

    // ---- ww[k] = np.sum(W[k]*W[k]) with numpy pairwise-8 rounding order ----
    if (tid < K) {
        const float* w = W + (size_t)tid * D;
        float r0 = __fmul_rn(w[0], w[0]);
        float r1 = __fmul_rn(w[1], w[1]);
        float r2 = __fmul_rn(w[2], w[2]);
        float r3 = __fmul_rn(w[3], w[3]);
        float r4 = __fmul_rn(w[4], w[4]);
        float r5 = __fmul_rn(w[5], w[5]);
        float r6 = __fmul_rn(w[6], w[6]);
        float r7 = __fmul_rn(w[7], w[7]);
        #pragma unroll 1
        for (int i = 8; i < D; i += 8) {
            r0 = __fadd_rn(r0, __fmul_rn(w[i + 0], w[i + 0]));
            r1 = __fadd_rn(r1, __fmul_rn(w[i + 1], w[i + 1]));
            r2 = __fadd_rn(r2, __fmul_rn(w[i + 2], w[i + 2]));
            r3 = __fadd_rn(r3, __fmul_rn(w[i + 3], w[i + 3]));
            r4 = __fadd_rn(r4, __fmul_rn(w[i + 4], w[i + 4]));
            r5 = __fadd_rn(r5, __fmul_rn(w[i + 5], w[i + 5]));
            r6 = __fadd_rn(r6, __fmul_rn(w[i + 6], w[i + 6]));
            r7 = __fadd_rn(r7, __fmul_rn(w[i + 7], w[i + 7]));
        }
        float a01 = __fadd_rn(r0, r1);
        float a23 = __fadd_rn(r2, r3);
        float a45 = __fadd_rn(r4, r5);
        float a67 = __fadd_rn(r6, r7);
        ww_lds[tid] = __fadd_rn(__fadd_rn(a01, a23), __fadd_rn(a45, a67));
    }
    __syncthreads();

    int bestk = 0;
    const bool valid = (row < (long long)n_rows);
    if (valid) {
        // ---- load x row into registers (kept in VGPRs via full unroll) ----
        float x[D];
        const float4* xr = (const float4*)(z + row * D);
        #pragma unroll
        for (int i = 0; i < D / 4; i++) {
            float4 v = xr[i];
            x[4 * i + 0] = v.x;
            x[4 * i + 1] = v.y;
            x[4 * i + 2] = v.z;
            x[4 * i + 3] = v.w;
        }

        // ---- xx = np.sum(x*x) with numpy pairwise-8 rounding order ----
        float r0 = __fmul_rn(x[0], x[0]);
        float r1 = __fmul_rn(x[1], x[1]);
        float r2 = __fmul_rn(x[2], x[2]);
        float r3 = __fmul_rn(x[3], x[3]);
        float r4 = __fmul_rn(x[4], x[4]);
        float r5 = __fmul_rn(x[5], x[5]);
        float r6 = __fmul_rn(x[6], x[6]);
        float r7 = __fmul_rn(x[7], x[7]);
        #pragma unroll
        for (int i = 8; i < D; i += 8) {
            r0 = __fadd_rn(r0, __fmul_rn(x[i + 0], x[i + 0]));
            r1 = __fadd_rn(r1, __fmul_rn(x[i + 1], x[i + 1]));
            r2 = __fadd_rn(r2, __fmul_rn(x[i + 2], x[i + 2]));
            r3 = __fadd_rn(r3, __fmul_rn(x[i + 3], x[i + 3]));
            r4 = __fadd_rn(r4, __fmul_rn(x[i + 4], x[i + 4]));
            r5 = __fadd_rn(r5, __fmul_rn(x[i + 5], x[i + 5]));
            r6 = __fadd_rn(r6, __fmul_rn(x[i + 6], x[i + 6]));
            r7 = __fadd_rn(r7, __fmul_rn(x[i + 7], x[i + 7]));
        }
        float a01 = __fadd_rn(r0, r1);
        float a23 = __fadd_rn(r2, r3);
        float a45 = __fadd_rn(r4, r5);
        float a67 = __fadd_rn(r6, r7);
        const float xx = __fadd_rn(__fadd_rn(a01, a23), __fadd_rn(a45, a67));

        // ---- k loop: 4 independent sequential-FMA dot chains ----
        float bestd = INFINITY;
        #pragma unroll 1
        for (int k0 = 0; k0 < K; k0 += 4) {
            const float* __restrict__ w0 = W + (size_t)k0 * D;
            float acc0 = 0.0f, acc1 = 0.0f, acc2 = 0.0f, acc3 = 0.0f;
            #pragma unroll
            for (int i = 0; i < D; i += 4) {
                const float4 a = *(const float4*)(w0 + i);
                const float4 b = *(const float4*)(w0 + D + i);
                const float4 c = *(const float4*)(w0 + 2 * D + i);
                const float4 e = *(const float4*)(w0 + 3 * D + i);
                acc0 = __fmaf_rn(x[i + 0], a.x, acc0);
                acc0 = __fmaf_rn(x[i + 1], a.y, acc0);
                acc0 = __fmaf_rn(x[i + 2], a.z, acc0);
                acc0 = __fmaf_rn(x[i + 3], a.w, acc0);
                acc1 = __fmaf_rn(x[i + 0], b.x, acc1);
                acc1 = __fmaf_rn(x[i + 1], b.y, acc1);
                acc1 = __fmaf_rn(x[i + 2], b.z, acc1);
                acc1 = __fmaf_rn(x[i + 3], b.w, acc1);
                acc2 = __fmaf_rn(x[i + 0], c.x, acc2);
                acc2 = __fmaf_rn(x[i + 1], c.y, acc2);
                acc2 = __fmaf_rn(x[i + 2], c.z, acc2);
                acc2 = __fmaf_rn(x[i + 3], c.w, acc2);
                acc3 = __fmaf_rn(x[i + 0], e.x, acc3);
                acc3 = __fmaf_rn(x[i + 1], e.y, acc3);
                acc3 = __fmaf_rn(x[i + 2], e.z, acc3);
                acc3 = __fmaf_rn(x[i + 3], e.w, acc3);
            }
            // d2 = (xx - 2*dot) + ww, left-to-right like numpy
            float d0 = __fadd_rn(__fsub_rn(xx, __fmul_rn(2.0f, acc0)), ww_lds[k0 + 0]);
            if (d0 < bestd) { bestd = d0; bestk = k0 + 0; }
            float d1 = __fadd_rn(__fsub_rn(xx, __fmul_rn(2.0f, acc1)), ww_lds[k0 + 1]);
            if (d1 < bestd) { bestd = d1; bestk = k0 + 1; }
            float d2 = __fadd_rn(__fsub_rn(xx, __fmul_rn(2.0f, acc2)), ww_lds[k0 + 2]);
            if (d2 < bestd) { bestd = d2; bestk = k0 + 2; }
            float d3 = __fadd_rn(__fsub_rn(xx, __fmul_rn(2.0f, acc3)), ww_lds[k0 + 3]);
            if (d3 < bestd) { bestd = d3; bestk = k0 + 3; }
        }
    }
    best_lds[tid] = bestk;
    __syncthreads();

    // ---- cooperative coalesced epilogue: 32 lanes per row ----
    const int sub = tid & 31;   // lane within row-group: covers 128 floats as float4
    const int grp = tid >> 5;   // 0..7: which row of the current batch of 8
    const long long blockRow0 = (long long)blockIdx.x * 256;
    float4* out4 = (float4*)out;
    const long long half = (long long)n_rows * (D / 4);
    #pragma unroll 1
    for (int r = grp; r < 256; r += 8) {
        const long long orow = blockRow0 + r;
        if (orow >= (long long)n_rows) break;
        const int bk = best_lds[r];
        const float4 v = *(const float4*)(W + (size_t)bk * D + sub * 4);
        const long long o = orow * (D / 4) + sub;
        out4[o] = v;         // z_q
        out4[o + half] = v;  // emb
    }
}

extern "C" void kernel_launch(void* const* d_in, const int* in_sizes, int n_in,
                              void* d_out, int out_size, void* d_ws, size_t ws_size,
                              hipStream_t stream) {
    const float* z = (const float*)d_in[0];
    const float* W = (const float*)d_in[1];
    float* out = (float*)d_out;
    const int n_rows = in_sizes[0] / D;  // 500000
    const int blocks = (n_rows + 255) / 256;
    vq_main_kernel<<<dim3(blocks), dim3(256), 0, stream>>>(z, W, out, n_rows);
}

// Round 2
// 844.079 us; speedup vs baseline: 1.1525x; 1.1525x over previous
//
#include <hip/hip_runtime.h>
#include <math.h>

#define D 128
#define K 128
#define HALFK 64

// One row per thread. x[128] pinned in VGPRs via asm; W streamed through LDS
// (32 KB half-tiles) with wave-uniform ds_read_b128 broadcast. Distances in
// fp32 with the round-1 recipe (validated: pairwise-8 norms, sequential-FMA
// dot, (xx - 2*dot) + ww, strict < ascending-k tie-break).
__global__ __launch_bounds__(256, 3) void vq_main_kernel(
    const float* __restrict__ z,
    const float* __restrict__ W,
    float* __restrict__ out,
    int n_rows)
{
    __shared__ float Wlds[HALFK * D];   // 32 KB, reused for both K-halves
    __shared__ float ww_lds[K];
    __shared__ int   best_lds[256];

    const int tid = threadIdx.x;
    const long long row = (long long)blockIdx.x * 256 + tid;
    const bool valid = (row < (long long)n_rows);

    // ---- ww[k] = np.sum(W[k]*W[k]) with numpy pairwise-8 rounding order ----
    if (tid < K) {
        const float* w = W + (size_t)tid * D;
        float r0 = __fmul_rn(w[0], w[0]);
        float r1 = __fmul_rn(w[1], w[1]);
        float r2 = __fmul_rn(w[2], w[2]);
        float r3 = __fmul_rn(w[3], w[3]);
        float r4 = __fmul_rn(w[4], w[4]);
        float r5 = __fmul_rn(w[5], w[5]);
        float r6 = __fmul_rn(w[6], w[6]);
        float r7 = __fmul_rn(w[7], w[7]);
        #pragma unroll 1
        for (int i = 8; i < D; i += 8) {
            r0 = __fadd_rn(r0, __fmul_rn(w[i + 0], w[i + 0]));
            r1 = __fadd_rn(r1, __fmul_rn(w[i + 1], w[i + 1]));
            r2 = __fadd_rn(r2, __fmul_rn(w[i + 2], w[i + 2]));
            r3 = __fadd_rn(r3, __fmul_rn(w[i + 3], w[i + 3]));
            r4 = __fadd_rn(r4, __fmul_rn(w[i + 4], w[i + 4]));
            r5 = __fadd_rn(r5, __fmul_rn(w[i + 5], w[i + 5]));
            r6 = __fadd_rn(r6, __fmul_rn(w[i + 6], w[i + 6]));
            r7 = __fadd_rn(r7, __fmul_rn(w[i + 7], w[i + 7]));
        }
        float a01 = __fadd_rn(r0, r1);
        float a23 = __fadd_rn(r2, r3);
        float a45 = __fadd_rn(r4, r5);
        float a67 = __fadd_rn(r6, r7);
        ww_lds[tid] = __fadd_rn(__fadd_rn(a01, a23), __fadd_rn(a45, a67));
    }

    // ---- stage W rows [0,64) into LDS (coalesced float4) ----
    {
        const float4* src = (const float4*)W;
        float4* dst = (float4*)Wlds;
        #pragma unroll
        for (int j = 0; j < (HALFK * D / 4) / 256; j++)
            dst[j * 256 + tid] = src[j * 256 + tid];
    }

    // ---- load x row into registers and pin them there ----
    float x[D];
    float xx = 0.0f;
    if (valid) {
        const float4* xr = (const float4*)(z + row * D);
        #pragma unroll
        for (int i = 0; i < D / 4; i++) {
            float4 v = xr[i];
            x[4 * i + 0] = v.x;
            x[4 * i + 1] = v.y;
            x[4 * i + 2] = v.z;
            x[4 * i + 3] = v.w;
        }
        // Opaque pin: prevents load-rematerialization (round 1: VGPR=76, x
        // was re-loaded from global inside the k-loop).
        #pragma unroll
        for (int i = 0; i < D; i++) asm volatile("" : "+v"(x[i]));

        // xx = np.sum(x*x), numpy pairwise-8 order
        float r0 = __fmul_rn(x[0], x[0]);
        float r1 = __fmul_rn(x[1], x[1]);
        float r2 = __fmul_rn(x[2], x[2]);
        float r3 = __fmul_rn(x[3], x[3]);
        float r4 = __fmul_rn(x[4], x[4]);
        float r5 = __fmul_rn(x[5], x[5]);
        float r6 = __fmul_rn(x[6], x[6]);
        float r7 = __fmul_rn(x[7], x[7]);
        #pragma unroll
        for (int i = 8; i < D; i += 8) {
            r0 = __fadd_rn(r0, __fmul_rn(x[i + 0], x[i + 0]));
            r1 = __fadd_rn(r1, __fmul_rn(x[i + 1], x[i + 1]));
            r2 = __fadd_rn(r2, __fmul_rn(x[i + 2], x[i + 2]));
            r3 = __fadd_rn(r3, __fmul_rn(x[i + 3], x[i + 3]));
            r4 = __fadd_rn(r4, __fmul_rn(x[i + 4], x[i + 4]));
            r5 = __fadd_rn(r5, __fmul_rn(x[i + 5], x[i + 5]));
            r6 = __fadd_rn(r6, __fmul_rn(x[i + 6], x[i + 6]));
            r7 = __fadd_rn(r7, __fmul_rn(x[i + 7], x[i + 7]));
        }
        float a01 = __fadd_rn(r0, r1);
        float a23 = __fadd_rn(r2, r3);
        float a45 = __fadd_rn(r4, r5);
        float a67 = __fadd_rn(r6, r7);
        xx = __fadd_rn(__fadd_rn(a01, a23), __fadd_rn(a45, a67));
    }
    __syncthreads();

    float bestd = INFINITY;
    int bestk = 0;

    // ---- K-phase 0: k in [0,64) from LDS ----
    if (valid) {
        #pragma unroll 1
        for (int kg = 0; kg < HALFK; kg += 2) {
            const float* w0 = &Wlds[kg * D];
            float acc0 = 0.0f, acc1 = 0.0f;
            #pragma unroll
            for (int i = 0; i < D; i += 4) {
                const float4 a = *(const float4*)(w0 + i);       // uniform ds_read_b128
                const float4 b = *(const float4*)(w0 + D + i);
                acc0 = __fmaf_rn(x[i + 0], a.x, acc0);
                acc0 = __fmaf_rn(x[i + 1], a.y, acc0);
                acc0 = __fmaf_rn(x[i + 2], a.z, acc0);
                acc0 = __fmaf_rn(x[i + 3], a.w, acc0);
                acc1 = __fmaf_rn(x[i + 0], b.x, acc1);
                acc1 = __fmaf_rn(x[i + 1], b.y, acc1);
                acc1 = __fmaf_rn(x[i + 2], b.z, acc1);
                acc1 = __fmaf_rn(x[i + 3], b.w, acc1);
            }
            float d0 = __fadd_rn(__fsub_rn(xx, __fmul_rn(2.0f, acc0)), ww_lds[kg + 0]);
            if (d0 < bestd) { bestd = d0; bestk = kg + 0; }
            float d1 = __fadd_rn(__fsub_rn(xx, __fmul_rn(2.0f, acc1)), ww_lds[kg + 1]);
            if (d1 < bestd) { bestd = d1; bestk = kg + 1; }
        }
    }
    __syncthreads();

    // ---- stage W rows [64,128) ----
    {
        const float4* src = (const float4*)(W + (size_t)HALFK * D);
        float4* dst = (float4*)Wlds;
        #pragma unroll
        for (int j = 0; j < (HALFK * D / 4) / 256; j++)
            dst[j * 256 + tid] = src[j * 256 + tid];
    }
    __syncthreads();

    // ---- K-phase 1: k in [64,128) ----
    if (valid) {
        #pragma unroll 1
        for (int kg = 0; kg < HALFK; kg += 2) {
            const float* w0 = &Wlds[kg * D];
            float acc0 = 0.0f, acc1 = 0.0f;
            #pragma unroll
            for (int i = 0; i < D; i += 4) {
                const float4 a = *(const float4*)(w0 + i);
                const float4 b = *(const float4*)(w0 + D + i);
                acc0 = __fmaf_rn(x[i + 0], a.x, acc0);
                acc0 = __fmaf_rn(x[i + 1], a.y, acc0);
                acc0 = __fmaf_rn(x[i + 2], a.z, acc0);
                acc0 = __fmaf_rn(x[i + 3], a.w, acc0);
                acc1 = __fmaf_rn(x[i + 0], b.x, acc1);
                acc1 = __fmaf_rn(x[i + 1], b.y, acc1);
                acc1 = __fmaf_rn(x[i + 2], b.z, acc1);
                acc1 = __fmaf_rn(x[i + 3], b.w, acc1);
            }
            float d0 = __fadd_rn(__fsub_rn(xx, __fmul_rn(2.0f, acc0)), ww_lds[HALFK + kg + 0]);
            if (d0 < bestd) { bestd = d0; bestk = HALFK + kg + 0; }
            float d1 = __fadd_rn(__fsub_rn(xx, __fmul_rn(2.0f, acc1)), ww_lds[HALFK + kg + 1]);
            if (d1 < bestd) { bestd = d1; bestk = HALFK + kg + 1; }
        }
    }
    best_lds[tid] = bestk;
    __syncthreads();

    // ---- cooperative coalesced epilogue: 32 lanes per row, W from L1 ----
    const int sub = tid & 31;
    const int grp = tid >> 5;
    const long long blockRow0 = (long long)blockIdx.x * 256;
    float4* out4 = (float4*)out;
    const long long half = (long long)n_rows * (D / 4);
    #pragma unroll 1
    for (int r = grp; r < 256; r += 8) {
        const long long orow = blockRow0 + r;
        if (orow >= (long long)n_rows) break;
        const int bk = best_lds[r];
        const float4 v = *(const float4*)(W + (size_t)bk * D + sub * 4);
        const long long o = orow * (D / 4) + sub;
        out4[o] = v;         // z_q
        out4[o + half] = v;  // emb
    }
}

extern "C" void kernel_launch(void* const* d_in, const int* in_sizes, int n_in,
                              void* d_out, int out_size, void* d_ws, size_t ws_size,
                              hipStream_t stream) {
    const float* z = (const float*)d_in[0];
    const float* W = (const float*)d_in[1];
    float* out = (float*)d_out;
    const int n_rows = in_sizes[0] / D;  // 500000
    const int blocks = (n_rows + 255) / 256;
    vq_main_kernel<<<dim3(blocks), dim3(256), 0, stream>>>(z, W, out, n_rows);
}